// Round 3
// baseline (1736.511 us; speedup 1.0000x reference)
//
#include <hip/hip_runtime.h>

// Kuramoto graph kernel, MI355X (gfx950) — v3.
// state: [N,64] f32; ind: [E,2] int32; w1,b1,w2: [64] f32; b2: [1] f32.
// out: [N,64] f32.
//
// v3: coarse-bucket records + fused LDS accumulate.
//   1) norm: nstate = row-normalized state (d_ws)
//   2) scatter: per edge (a,b), append record (a&63, b) to bucket a>>6 and
//      (b&63, a) to bucket b>>6. Only ~782 active write tails -> write-combines.
//   3) bucket_accum: one workgroup per bucket. 64 node rows + 64 accumulators
//      in LDS; per record recompute s, dE; accumulate dE*nbr via LDS atomics;
//      fused projection out = n*<n,acc> - acc; coalesced store. No global
//      atomics, no output memset.

#define D 64
#define NPB 64          // nodes per bucket
#define CAPB 4096       // records per bucket; mean 3200, +15.8 sigma

// ---------- helpers ----------

__device__ __forceinline__ float grpReduce16(float v) {
    v += __shfl_xor(v, 1, 64);
    v += __shfl_xor(v, 2, 64);
    v += __shfl_xor(v, 4, 64);
    v += __shfl_xor(v, 8, 64);
    return v;
}

__device__ __forceinline__ float waveReduceSum64(float v) {
    v += __shfl_xor(v, 32, 64);
    v += __shfl_xor(v, 16, 64);
    v += __shfl_xor(v, 8, 64);
    v += __shfl_xor(v, 4, 64);
    v += __shfl_xor(v, 2, 64);
    v += __shfl_xor(v, 1, 64);
    return v;
}

__device__ __forceinline__ float dot4(float4 a, float4 b) {
    return fmaf(a.x, b.x, fmaf(a.y, b.y, fmaf(a.z, b.z, a.w * b.w)));
}

// gelu_tanh(x) = 0.5*x*(1+tanh(t)) = x * sigmoid(2t), t = c*(x + 0.044715 x^3)
// |x| <= ~10 here (s in [-1,1], w1/b1 ~ N(0,1)), so exp never overflows.
__device__ __forceinline__ float gelu_tanh(float x) {
    float u = -1.5957691216057308f * fmaf(0.044715f * x, x * x, x);  // -2t
    float e = __expf(u);
    return x * __builtin_amdgcn_rcpf(1.0f + e);
}

// ---------- row-normalize (16 lanes x float4 per row) ----------

__global__ void norm_kernel(const float4* __restrict__ state4,
                            float4* __restrict__ nstate4, int n_nodes) {
    int gid = blockIdx.x * blockDim.x + threadIdx.x;
    int row = gid >> 4;
    int gl  = threadIdx.x & 15;
    if (row >= n_nodes) return;
    float4 v = state4[row * 16 + gl];
    float ss = grpReduce16(dot4(v, v));
    float inv = 1.0f / sqrtf(ss);
    float4 r = {v.x * inv, v.y * inv, v.z * inv, v.w * inv};
    nstate4[row * 16 + gl] = r;
}

// ---------- scatter endpoint records into coarse buckets ----------

__global__ void scatter_bucket_kernel(const int* __restrict__ ind,
                                      int* __restrict__ bcnt,
                                      int2* __restrict__ recs, int n_edges) {
    int i = blockIdx.x * blockDim.x + threadIdx.x;
    if (i >= n_edges) return;
    int2 e = ((const int2*)ind)[i];
    int ba = e.x >> 6, bb = e.y >> 6;
    int sa = atomicAdd(&bcnt[ba], 1);
    if (sa < CAPB) recs[(size_t)ba * CAPB + sa] = make_int2(e.x & 63, e.y);
    int sb = atomicAdd(&bcnt[bb], 1);
    if (sb < CAPB) recs[(size_t)bb * CAPB + sb] = make_int2(e.y & 63, e.x);
}

// ---------- fused accumulate + projection, one workgroup per bucket ----------

__global__ void __launch_bounds__(256) bucket_accum_kernel(
        const float4* __restrict__ nstate4,
        const int* __restrict__ bcnt,
        const int2* __restrict__ recs,
        const float4* __restrict__ w1_4,
        const float4* __restrict__ b1_4,
        const float4* __restrict__ w2_4,
        const float* __restrict__ b2,
        float4* __restrict__ out4, int n_nodes) {
    __shared__ float rows[NPB * D];   // 16 KB
    __shared__ float accs[NPB * D];   // 16 KB

    int blk = blockIdx.x;
    int node0 = blk * NPB;
    int tid = threadIdx.x;

    // cooperative load of 64 node rows; zero accumulators
    for (int i = tid; i < NPB * 16; i += 256) {
        int r = i >> 4;
        int node = node0 + r;
        float4 v = (node < n_nodes) ? nstate4[(size_t)node * 16 + (i & 15)]
                                    : make_float4(0.f, 0.f, 0.f, 0.f);
        ((float4*)rows)[i] = v;
        ((float4*)accs)[i] = make_float4(0.f, 0.f, 0.f, 0.f);
    }
    __syncthreads();

    int wid = tid >> 6, lane = tid & 63;
    int grp = lane >> 4, gl = lane & 15;

    float4 W1 = w1_4[gl];
    float4 B1 = b1_4[gl];
    float4 W2 = w2_4[gl];
    float  B2 = b2[0];

    int cnt = min(bcnt[blk], CAPB);
    const int2* rb = recs + (size_t)blk * CAPB;

    // 4 waves x 4 groups = 16 records per block-iteration
    for (int idx = wid * 4 + grp; idx < cnt; idx += 16) {
        int2 rec = rb[idx];                           // (local node, neighbor)
        float4 x = nstate4[(size_t)rec.y * 16 + gl];  // neighbor row (global)
        float4 m = ((const float4*)rows)[rec.x * 16 + gl];

        float s = grpReduce16(dot4(m, x));

        float h = gelu_tanh(fmaf(s, W1.x, B1.x)) * W2.x;
        h      += gelu_tanh(fmaf(s, W1.y, B1.y)) * W2.y;
        h      += gelu_tanh(fmaf(s, W1.z, B1.z)) * W2.z;
        h      += gelu_tanh(fmaf(s, W1.w, B1.w)) * W2.w;
        float dE = grpReduce16(h) + B2;

        float* a = &accs[rec.x * D + gl * 4];
        atomicAdd(a + 0, dE * x.x);
        atomicAdd(a + 1, dE * x.y);
        atomicAdd(a + 2, dE * x.z);
        atomicAdd(a + 3, dE * x.w);
    }
    __syncthreads();

    // fused projection: out = n * <n, acc> - acc
    for (int j = wid * 4 + grp; j < NPB; j += 16) {
        int node = node0 + j;
        if (node >= n_nodes) continue;
        float4 a = ((const float4*)accs)[j * 16 + gl];
        float4 m = ((const float4*)rows)[j * 16 + gl];
        float d2 = grpReduce16(dot4(m, a));
        float4 r;
        r.x = fmaf(m.x, d2, -a.x);
        r.y = fmaf(m.y, d2, -a.y);
        r.z = fmaf(m.z, d2, -a.z);
        r.w = fmaf(m.w, d2, -a.w);
        out4[(size_t)node * 16 + gl] = r;
    }
}

// ---------- v1 fallback (edge-parallel, atomic output) ----------

__global__ void edge_kernel(const float* __restrict__ nstate,
                            const int* __restrict__ ind,
                            const float* __restrict__ w1,
                            const float* __restrict__ b1,
                            const float* __restrict__ w2,
                            const float* __restrict__ b2,
                            float* __restrict__ acc, int n_edges) {
    int gid = blockIdx.x * blockDim.x + threadIdx.x;
    int edge = gid >> 6;
    int lane = threadIdx.x & 63;
    if (edge >= n_edges) return;
    const int2 e = ((const int2*)ind)[edge];
    float sv = nstate[e.x * D + lane];
    float dv = nstate[e.y * D + lane];
    float s = waveReduceSum64(sv * dv);
    float x = fmaf(s, w1[lane], b1[lane]);
    float h = gelu_tanh(x) * w2[lane];
    float dE = waveReduceSum64(h) + b2[0];
    atomicAdd(&acc[e.x * D + lane], dE * dv);
    atomicAdd(&acc[e.y * D + lane], dE * sv);
}

__global__ void final_kernel(const float* __restrict__ nstate,
                             float* __restrict__ out, int n_nodes) {
    int gid = blockIdx.x * blockDim.x + threadIdx.x;
    int row = gid >> 6;
    int lane = threadIdx.x & 63;
    if (row >= n_nodes) return;
    float a = out[row * D + lane];
    float n = nstate[row * D + lane];
    float dot = waveReduceSum64(n * a);
    out[row * D + lane] = fmaf(n, dot, -a);
}

// ---------- launch ----------

extern "C" void kernel_launch(void* const* d_in, const int* in_sizes, int n_in,
                              void* d_out, int out_size, void* d_ws, size_t ws_size,
                              hipStream_t stream) {
    const float* state = (const float*)d_in[0];
    const int*   ind   = (const int*)d_in[1];
    const float* w1    = (const float*)d_in[2];
    const float* b1    = (const float*)d_in[3];
    const float* w2    = (const float*)d_in[4];
    const float* b2    = (const float*)d_in[5];

    int n_nodes = in_sizes[0] / D;
    int n_edges = in_sizes[1] / 2;
    int n_buckets = (n_nodes + NPB - 1) / NPB;

    // workspace layout
    size_t nstate_bytes = (size_t)n_nodes * D * sizeof(float);
    size_t bcnt_off     = (nstate_bytes + 255) & ~(size_t)255;
    size_t bcnt_bytes   = (size_t)n_buckets * sizeof(int);
    size_t recs_off     = (bcnt_off + bcnt_bytes + 255) & ~(size_t)255;
    size_t recs_bytes   = (size_t)n_buckets * CAPB * sizeof(int2);
    size_t needed       = recs_off + recs_bytes;

    float* nstate = (float*)d_ws;
    const int threads = 256;

    int norm_blocks = (n_nodes * 16 + threads - 1) / threads;
    norm_kernel<<<norm_blocks, threads, 0, stream>>>(
        (const float4*)state, (float4*)nstate, n_nodes);

    if (ws_size >= needed) {
        int*  bcnt = (int*)((char*)d_ws + bcnt_off);
        int2* recs = (int2*)((char*)d_ws + recs_off);
        hipMemsetAsync(bcnt, 0, bcnt_bytes, stream);

        int sc_blocks = (n_edges + threads - 1) / threads;
        scatter_bucket_kernel<<<sc_blocks, threads, 0, stream>>>(
            ind, bcnt, recs, n_edges);

        bucket_accum_kernel<<<n_buckets, threads, 0, stream>>>(
            (const float4*)nstate, bcnt, recs,
            (const float4*)w1, (const float4*)b1, (const float4*)w2, b2,
            (float4*)d_out, n_nodes);
    } else {
        // fallback: edge-parallel with atomics into d_out
        hipMemsetAsync(d_out, 0, (size_t)out_size * sizeof(float), stream);
        long long total = (long long)n_edges * D;
        int edge_blocks = (int)((total + threads - 1) / threads);
        edge_kernel<<<edge_blocks, threads, 0, stream>>>(
            nstate, ind, w1, b1, w2, b2, (float*)d_out, n_edges);
        int node_blocks = (n_nodes * D + threads - 1) / threads;
        final_kernel<<<node_blocks, threads, 0, stream>>>(nstate, (float*)d_out, n_nodes);
    }
}

// Round 4
// 666.006 us; speedup vs baseline: 2.6073x; 2.6073x over previous
//
#include <hip/hip_runtime.h>

// Kuramoto graph kernel, MI355X (gfx950) — v4.
// state: [N,64] f32; ind: [E,2] int32; w1,b1,w2: [64] f32; b2: [1] f32.
// out: [N,64] f32.
//
// v4 = v2 structure with the scatter replaced by a filter-scan CSR build:
//   1) norm: nstate = row-normalized state (d_ws)
//   2) build_csr: 25 blocks x 1024 threads; block b owns nodes
//      [b*2048, (b+1)*2048). Streams the whole edge list (coalesced, L2/L3
//      -served); matching endpoints take a slot from an LDS cursor (LDS
//      atomics, no global atomics) and store the neighbor into a per-node
//      padded list. Store region per block = 1 MB -> L2-resident.
//   3) accum: one wave per node, 4 neighbors in flight (16-lane groups),
//      recompute s and dE per edge, accumulate in registers, fused
//      projection, one coalesced store per node. No global atomics anywhere.

#define D 64
#define CAP 128     // max degree; Poisson(50) tail at 128 ~ 5e-19
#define NPB2 2048   // nodes per build block

// ---------- helpers ----------

__device__ __forceinline__ float grpReduce16(float v) {
    v += __shfl_xor(v, 1, 64);
    v += __shfl_xor(v, 2, 64);
    v += __shfl_xor(v, 4, 64);
    v += __shfl_xor(v, 8, 64);
    return v;
}

__device__ __forceinline__ float waveReduceSum64(float v) {
    v += __shfl_xor(v, 32, 64);
    v += __shfl_xor(v, 16, 64);
    v += __shfl_xor(v, 8, 64);
    v += __shfl_xor(v, 4, 64);
    v += __shfl_xor(v, 2, 64);
    v += __shfl_xor(v, 1, 64);
    return v;
}

__device__ __forceinline__ float dot4(float4 a, float4 b) {
    return fmaf(a.x, b.x, fmaf(a.y, b.y, fmaf(a.z, b.z, a.w * b.w)));
}

// gelu_tanh(x) = x * sigmoid(2t), t = sqrt(2/pi)*(x + 0.044715 x^3)
// |x| small here (s in [-1,1], w1/b1 ~ N(0,1)); exp never overflows.
__device__ __forceinline__ float gelu_tanh(float x) {
    float u = -1.5957691216057308f * fmaf(0.044715f * x, x * x, x);  // -2t
    float e = __expf(u);
    return x * __builtin_amdgcn_rcpf(1.0f + e);
}

// ---------- row-normalize (16 lanes x float4 per row) ----------

__global__ void norm_kernel(const float4* __restrict__ state4,
                            float4* __restrict__ nstate4, int n_nodes) {
    int gid = blockIdx.x * blockDim.x + threadIdx.x;
    int row = gid >> 4;
    int gl  = threadIdx.x & 15;
    if (row >= n_nodes) return;
    float4 v = state4[row * 16 + gl];
    float ss = grpReduce16(dot4(v, v));
    float inv = 1.0f / sqrtf(ss);
    float4 r = {v.x * inv, v.y * inv, v.z * inv, v.w * inv};
    nstate4[row * 16 + gl] = r;
}

// ---------- filter-scan CSR build: one block per 2048-node range ----------

__global__ void __launch_bounds__(1024) build_csr_kernel(
        const int2* __restrict__ ind2,
        int* __restrict__ deg,
        int* __restrict__ entries, int n_edges, int n_nodes) {
    __shared__ int cur[NPB2];
    int tid = threadIdx.x;
    int node0 = blockIdx.x * NPB2;

    for (int i = tid; i < NPB2; i += 1024) cur[i] = 0;
    __syncthreads();

    for (int i = tid; i < n_edges; i += 1024) {
        int2 e = ind2[i];
        unsigned la = (unsigned)(e.x - node0);
        if (la < NPB2) {
            int s = atomicAdd(&cur[la], 1);
            if (s < CAP) entries[(size_t)e.x * CAP + s] = e.y;
        }
        unsigned lb = (unsigned)(e.y - node0);
        if (lb < NPB2) {
            int s = atomicAdd(&cur[lb], 1);
            if (s < CAP) entries[(size_t)e.y * CAP + s] = e.x;
        }
    }
    __syncthreads();

    for (int i = tid; i < NPB2; i += 1024) {
        int node = node0 + i;
        if (node < n_nodes) deg[node] = min(cur[i], CAP);
    }
}

// ---------- accumulate + fused projection: one wave per node ----------

__global__ void __launch_bounds__(256) accum_kernel(
        const float4* __restrict__ nstate4,
        const int* __restrict__ deg,
        const int* __restrict__ entries,
        const float4* __restrict__ w1_4,
        const float4* __restrict__ b1_4,
        const float4* __restrict__ w2_4,
        const float* __restrict__ b2,
        float4* __restrict__ out4, int n_nodes) {
    int node = blockIdx.x * (blockDim.x >> 6) + (threadIdx.x >> 6);
    if (node >= n_nodes) return;
    int lane = threadIdx.x & 63;
    int grp  = lane >> 4;   // which of 4 neighbors per iteration
    int gl   = lane & 15;   // dims [4*gl .. 4*gl+3]

    float4 my = nstate4[(size_t)node * 16 + gl];
    float4 W1 = w1_4[gl];
    float4 B1 = b1_4[gl];
    float4 W2 = w2_4[gl];
    float  B2 = b2[0];

    int dg = deg[node];
    const int* ebase = entries + (size_t)node * CAP;

    float4 acc = {0.f, 0.f, 0.f, 0.f};
    for (int k0 = 0; k0 < dg; k0 += 4) {
        int idx = k0 + grp;
        bool valid = idx < dg;
        int nbr = valid ? ebase[idx] : 0;
        float4 x = nstate4[(size_t)nbr * 16 + gl];

        float s = grpReduce16(dot4(my, x));

        float h = gelu_tanh(fmaf(s, W1.x, B1.x)) * W2.x;
        h      += gelu_tanh(fmaf(s, W1.y, B1.y)) * W2.y;
        h      += gelu_tanh(fmaf(s, W1.z, B1.z)) * W2.z;
        h      += gelu_tanh(fmaf(s, W1.w, B1.w)) * W2.w;
        float dE = grpReduce16(h) + B2;
        if (!valid) dE = 0.0f;

        acc.x = fmaf(dE, x.x, acc.x);
        acc.y = fmaf(dE, x.y, acc.y);
        acc.z = fmaf(dE, x.z, acc.z);
        acc.w = fmaf(dE, x.w, acc.w);
    }

    // sum the 4 groups' partials (each lane-set covers all 64 dims)
    acc.x += __shfl_xor(acc.x, 16, 64); acc.x += __shfl_xor(acc.x, 32, 64);
    acc.y += __shfl_xor(acc.y, 16, 64); acc.y += __shfl_xor(acc.y, 32, 64);
    acc.z += __shfl_xor(acc.z, 16, 64); acc.z += __shfl_xor(acc.z, 32, 64);
    acc.w += __shfl_xor(acc.w, 16, 64); acc.w += __shfl_xor(acc.w, 32, 64);

    // out = n * <n, acc> - acc
    float d2 = grpReduce16(dot4(my, acc));
    float4 r;
    r.x = fmaf(my.x, d2, -acc.x);
    r.y = fmaf(my.y, d2, -acc.y);
    r.z = fmaf(my.z, d2, -acc.z);
    r.w = fmaf(my.w, d2, -acc.w);
    if (grp == 0) out4[(size_t)node * 16 + gl] = r;
}

// ---------- v1 fallback (edge-parallel, atomic output) ----------

__global__ void edge_kernel(const float* __restrict__ nstate,
                            const int* __restrict__ ind,
                            const float* __restrict__ w1,
                            const float* __restrict__ b1,
                            const float* __restrict__ w2,
                            const float* __restrict__ b2,
                            float* __restrict__ acc, int n_edges) {
    int gid = blockIdx.x * blockDim.x + threadIdx.x;
    int edge = gid >> 6;
    int lane = threadIdx.x & 63;
    if (edge >= n_edges) return;
    const int2 e = ((const int2*)ind)[edge];
    float sv = nstate[e.x * D + lane];
    float dv = nstate[e.y * D + lane];
    float s = waveReduceSum64(sv * dv);
    float x = fmaf(s, w1[lane], b1[lane]);
    float h = gelu_tanh(x) * w2[lane];
    float dE = waveReduceSum64(h) + b2[0];
    atomicAdd(&acc[e.x * D + lane], dE * dv);
    atomicAdd(&acc[e.y * D + lane], dE * sv);
}

__global__ void final_kernel(const float* __restrict__ nstate,
                             float* __restrict__ out, int n_nodes) {
    int gid = blockIdx.x * blockDim.x + threadIdx.x;
    int row = gid >> 6;
    int lane = threadIdx.x & 63;
    if (row >= n_nodes) return;
    float a = out[row * D + lane];
    float n = nstate[row * D + lane];
    float dot = waveReduceSum64(n * a);
    out[row * D + lane] = fmaf(n, dot, -a);
}

// ---------- launch ----------

extern "C" void kernel_launch(void* const* d_in, const int* in_sizes, int n_in,
                              void* d_out, int out_size, void* d_ws, size_t ws_size,
                              hipStream_t stream) {
    const float* state = (const float*)d_in[0];
    const int*   ind   = (const int*)d_in[1];
    const float* w1    = (const float*)d_in[2];
    const float* b1    = (const float*)d_in[3];
    const float* w2    = (const float*)d_in[4];
    const float* b2    = (const float*)d_in[5];

    int n_nodes = in_sizes[0] / D;
    int n_edges = in_sizes[1] / 2;

    // workspace layout
    size_t nstate_bytes  = (size_t)n_nodes * D * sizeof(float);
    size_t deg_off       = (nstate_bytes + 255) & ~(size_t)255;
    size_t deg_bytes     = (size_t)n_nodes * sizeof(int);
    size_t entries_off   = (deg_off + deg_bytes + 255) & ~(size_t)255;
    size_t entries_bytes = (size_t)n_nodes * CAP * sizeof(int);
    size_t needed        = entries_off + entries_bytes;

    float* nstate = (float*)d_ws;
    const int threads = 256;

    int norm_blocks = (n_nodes * 16 + threads - 1) / threads;
    norm_kernel<<<norm_blocks, threads, 0, stream>>>(
        (const float4*)state, (float4*)nstate, n_nodes);

    if (ws_size >= needed) {
        int* deg     = (int*)((char*)d_ws + deg_off);
        int* entries = (int*)((char*)d_ws + entries_off);

        int build_blocks = (n_nodes + NPB2 - 1) / NPB2;
        build_csr_kernel<<<build_blocks, 1024, 0, stream>>>(
            (const int2*)ind, deg, entries, n_edges, n_nodes);

        int acc_blocks = (n_nodes + (threads / 64) - 1) / (threads / 64);
        accum_kernel<<<acc_blocks, threads, 0, stream>>>(
            (const float4*)nstate, deg, entries,
            (const float4*)w1, (const float4*)b1, (const float4*)w2, b2,
            (float4*)d_out, n_nodes);
    } else {
        // fallback: edge-parallel with atomics into d_out
        hipMemsetAsync(d_out, 0, (size_t)out_size * sizeof(float), stream);
        long long total = (long long)n_edges * D;
        int edge_blocks = (int)((total + threads - 1) / threads);
        edge_kernel<<<edge_blocks, threads, 0, stream>>>(
            nstate, ind, w1, b1, w2, b2, (float*)d_out, n_edges);
        int node_blocks = (n_nodes * D + threads - 1) / threads;
        final_kernel<<<node_blocks, threads, 0, stream>>>(nstate, (float*)d_out, n_nodes);
    }
}

// Round 5
// 248.772 us; speedup vs baseline: 6.9803x; 2.6772x over previous
//
#include <hip/hip_runtime.h>

// Kuramoto graph kernel, MI355X (gfx950) — v5.
// state: [N,64] f32; ind: [E,2] int32; w1,b1,w2: [64] f32; b2: [1] f32.
// out: [N,64] f32.
//
// v5 = v2 structure, with:
//   - XCD-sliced CSR build: nodes partitioned into 8 contiguous slices;
//     build blocks take slice = blockIdx%8 (round-robin dispatch -> one XCD
//     per slice), so each slice's 3.2 MB entry region stays in that XCD's
//     4 MB L2 (kills the RFO/writeback churn seen in v2: 242+155 MB).
//     1024 build blocks (vs v4's fatal 25). Cursors = 50k global atomics
//     (v2-proven regime).
//   - norm fused into the same launch (disjoint block range).
//   - f16 normalized gather table (one 128 B line per row): accum gather
//     volume 640 -> 320 MB; own-row normalization recomputed from f32 state.
//   - accum uses the same %8 slice mapping so entries/cursor reads hit the
//     still-warm local L2.

#define D 64
#define CAP 128     // max degree; Poisson(50) tail at 128 ~ 5e-19
#define NSLICE 8

typedef _Float16 h4 __attribute__((ext_vector_type(4)));

// ---------- helpers ----------

__device__ __forceinline__ float grpReduce16(float v) {
    v += __shfl_xor(v, 1, 64);
    v += __shfl_xor(v, 2, 64);
    v += __shfl_xor(v, 4, 64);
    v += __shfl_xor(v, 8, 64);
    return v;
}

__device__ __forceinline__ float waveReduceSum64(float v) {
    v += __shfl_xor(v, 32, 64);
    v += __shfl_xor(v, 16, 64);
    v += __shfl_xor(v, 8, 64);
    v += __shfl_xor(v, 4, 64);
    v += __shfl_xor(v, 2, 64);
    v += __shfl_xor(v, 1, 64);
    return v;
}

__device__ __forceinline__ float dot4(float4 a, float4 b) {
    return fmaf(a.x, b.x, fmaf(a.y, b.y, fmaf(a.z, b.z, a.w * b.w)));
}

// gelu_tanh(x) = x * sigmoid(2t), t = sqrt(2/pi)*(x + 0.044715 x^3)
__device__ __forceinline__ float gelu_tanh(float x) {
    float u = -1.5957691216057308f * fmaf(0.044715f * x, x * x, x);  // -2t
    float e = __expf(u);
    return x * __builtin_amdgcn_rcpf(1.0f + e);
}

// ---------- fused prep: norm (f16 table) + XCD-sliced CSR build ----------

__global__ void __launch_bounds__(256) prep_kernel(
        const float4* __restrict__ state4,
        h4* __restrict__ nh,
        int* __restrict__ cursor,
        int* __restrict__ entries,
        const long long* __restrict__ ind_ll,
        int n_nodes, int n_edges, int norm_blocks,
        int slice_n, int blocks_per_slice) {
    int bid = blockIdx.x;
    int tid = threadIdx.x;

    if (bid < norm_blocks) {
        // --- norm: 16 rows per block, 16 lanes x float4 per row ---
        int row = bid * 16 + (tid >> 4);
        int gl  = tid & 15;
        if (row < n_nodes) {
            float4 v = state4[(size_t)row * 16 + gl];
            float ss = grpReduce16(dot4(v, v));
            float inv = 1.0f / sqrtf(ss);
            h4 hv;
            hv.x = (_Float16)(v.x * inv);
            hv.y = (_Float16)(v.y * inv);
            hv.z = (_Float16)(v.z * inv);
            hv.w = (_Float16)(v.w * inv);
            nh[(size_t)row * 16 + gl] = hv;
        }
        return;
    }

    // --- build: block (slice, j) scans edge chunk j, keeps slice's nodes ---
    int b = bid - norm_blocks;
    int slice = b & (NSLICE - 1);
    int j = b >> 3;
    int lo = slice * slice_n;
    int hi = min(lo + slice_n, n_nodes);
    int e0 = (int)((long long)n_edges * j / blocks_per_slice);
    int e1 = (int)((long long)n_edges * (j + 1) / blocks_per_slice);

    for (int i = e0 + tid; i < e1; i += 256) {
        long long p = __builtin_nontemporal_load(ind_ll + i);
        int a = (int)p;
        int c = (int)(p >> 32);
        if (a >= lo && a < hi) {
            int s = atomicAdd(&cursor[a], 1);
            if (s < CAP) entries[(size_t)a * CAP + s] = c;
        }
        if (c >= lo && c < hi) {
            int s = atomicAdd(&cursor[c], 1);
            if (s < CAP) entries[(size_t)c * CAP + s] = a;
        }
    }
}

// ---------- accumulate + fused projection: one wave per node ----------

__global__ void __launch_bounds__(256) accum_kernel(
        const float4* __restrict__ state4,
        const h4* __restrict__ nh,
        const int* __restrict__ cursor,
        const int* __restrict__ entries,
        const float4* __restrict__ w1_4,
        const float4* __restrict__ b1_4,
        const float4* __restrict__ w2_4,
        const float* __restrict__ b2,
        float4* __restrict__ out4, int n_nodes, int slice_n) {
    int bid = blockIdx.x;
    int wid = threadIdx.x >> 6;
    int slice = bid & (NSLICE - 1);
    int local = (bid >> 3) * 4 + wid;
    if (local >= slice_n) return;
    int node = slice * slice_n + local;
    if (node >= n_nodes) return;

    int lane = threadIdx.x & 63;
    int grp  = lane >> 4;   // which of 4 neighbors per iteration
    int gl   = lane & 15;   // dims [4*gl .. 4*gl+3]

    // own row: read f32 state, normalize in-register
    float4 v = state4[(size_t)node * 16 + gl];
    float ss = grpReduce16(dot4(v, v));
    float inv = 1.0f / sqrtf(ss);
    float4 my = {v.x * inv, v.y * inv, v.z * inv, v.w * inv};

    float4 W1 = w1_4[gl];
    float4 B1 = b1_4[gl];
    float4 W2 = w2_4[gl];
    float  B2 = b2[0];

    int dg = min(cursor[node], CAP);
    const int* ebase = entries + (size_t)node * CAP;

    float4 acc = {0.f, 0.f, 0.f, 0.f};
    for (int k0 = 0; k0 < dg; k0 += 4) {
        int idx = k0 + grp;
        bool valid = idx < dg;
        int nbr = valid ? ebase[idx] : node;
        h4 xh = nh[(size_t)nbr * 16 + gl];
        float4 x = {(float)xh.x, (float)xh.y, (float)xh.z, (float)xh.w};

        float s = grpReduce16(dot4(my, x));

        float h = gelu_tanh(fmaf(s, W1.x, B1.x)) * W2.x;
        h      += gelu_tanh(fmaf(s, W1.y, B1.y)) * W2.y;
        h      += gelu_tanh(fmaf(s, W1.z, B1.z)) * W2.z;
        h      += gelu_tanh(fmaf(s, W1.w, B1.w)) * W2.w;
        float dE = grpReduce16(h) + B2;
        if (!valid) dE = 0.0f;

        acc.x = fmaf(dE, x.x, acc.x);
        acc.y = fmaf(dE, x.y, acc.y);
        acc.z = fmaf(dE, x.z, acc.z);
        acc.w = fmaf(dE, x.w, acc.w);
    }

    // sum the 4 groups' partials
    acc.x += __shfl_xor(acc.x, 16, 64); acc.x += __shfl_xor(acc.x, 32, 64);
    acc.y += __shfl_xor(acc.y, 16, 64); acc.y += __shfl_xor(acc.y, 32, 64);
    acc.z += __shfl_xor(acc.z, 16, 64); acc.z += __shfl_xor(acc.z, 32, 64);
    acc.w += __shfl_xor(acc.w, 16, 64); acc.w += __shfl_xor(acc.w, 32, 64);

    // out = n * <n, acc> - acc
    float d2 = grpReduce16(dot4(my, acc));
    float4 r;
    r.x = fmaf(my.x, d2, -acc.x);
    r.y = fmaf(my.y, d2, -acc.y);
    r.z = fmaf(my.z, d2, -acc.z);
    r.w = fmaf(my.w, d2, -acc.w);
    if (grp == 0) out4[(size_t)node * 16 + gl] = r;
}

// ---------- v1 fallback (edge-parallel, atomic output) ----------

__global__ void norm_f32_kernel(const float4* __restrict__ state4,
                                float4* __restrict__ nstate4, int n_nodes) {
    int gid = blockIdx.x * blockDim.x + threadIdx.x;
    int row = gid >> 4;
    int gl  = threadIdx.x & 15;
    if (row >= n_nodes) return;
    float4 v = state4[row * 16 + gl];
    float ss = grpReduce16(dot4(v, v));
    float inv = 1.0f / sqrtf(ss);
    float4 r = {v.x * inv, v.y * inv, v.z * inv, v.w * inv};
    nstate4[row * 16 + gl] = r;
}

__global__ void edge_kernel(const float* __restrict__ nstate,
                            const int* __restrict__ ind,
                            const float* __restrict__ w1,
                            const float* __restrict__ b1,
                            const float* __restrict__ w2,
                            const float* __restrict__ b2,
                            float* __restrict__ acc, int n_edges) {
    int gid = blockIdx.x * blockDim.x + threadIdx.x;
    int edge = gid >> 6;
    int lane = threadIdx.x & 63;
    if (edge >= n_edges) return;
    const int2 e = ((const int2*)ind)[edge];
    float sv = nstate[e.x * D + lane];
    float dv = nstate[e.y * D + lane];
    float s = waveReduceSum64(sv * dv);
    float x = fmaf(s, w1[lane], b1[lane]);
    float h = gelu_tanh(x) * w2[lane];
    float dE = waveReduceSum64(h) + b2[0];
    atomicAdd(&acc[e.x * D + lane], dE * dv);
    atomicAdd(&acc[e.y * D + lane], dE * sv);
}

__global__ void final_kernel(const float* __restrict__ nstate,
                             float* __restrict__ out, int n_nodes) {
    int gid = blockIdx.x * blockDim.x + threadIdx.x;
    int row = gid >> 6;
    int lane = threadIdx.x & 63;
    if (row >= n_nodes) return;
    float a = out[row * D + lane];
    float n = nstate[row * D + lane];
    float dot = waveReduceSum64(n * a);
    out[row * D + lane] = fmaf(n, dot, -a);
}

// ---------- launch ----------

extern "C" void kernel_launch(void* const* d_in, const int* in_sizes, int n_in,
                              void* d_out, int out_size, void* d_ws, size_t ws_size,
                              hipStream_t stream) {
    const float* state = (const float*)d_in[0];
    const int*   ind   = (const int*)d_in[1];
    const float* w1    = (const float*)d_in[2];
    const float* b1    = (const float*)d_in[3];
    const float* w2    = (const float*)d_in[4];
    const float* b2    = (const float*)d_in[5];

    int n_nodes = in_sizes[0] / D;
    int n_edges = in_sizes[1] / 2;
    int slice_n = (n_nodes + NSLICE - 1) / NSLICE;

    // workspace layout: f16 table + cursor + entries
    size_t nh_bytes      = (size_t)n_nodes * D * 2;            // 6.4 MB
    size_t cursor_off    = (nh_bytes + 255) & ~(size_t)255;
    size_t cursor_bytes  = (size_t)n_nodes * sizeof(int);
    size_t entries_off   = (cursor_off + cursor_bytes + 255) & ~(size_t)255;
    size_t entries_bytes = (size_t)n_nodes * CAP * sizeof(int);
    size_t needed        = entries_off + entries_bytes;

    const int threads = 256;

    if (ws_size >= needed) {
        h4*  nh      = (h4*)d_ws;
        int* cursor  = (int*)((char*)d_ws + cursor_off);
        int* entries = (int*)((char*)d_ws + entries_off);

        hipMemsetAsync(cursor, 0, cursor_bytes, stream);

        int norm_blocks = (((n_nodes + 15) / 16) + 7) & ~7;  // multiple of 8
        int bps = 128;                                       // build blocks per slice
        int grid = norm_blocks + bps * NSLICE;
        prep_kernel<<<grid, threads, 0, stream>>>(
            (const float4*)state, nh, cursor, entries,
            (const long long*)ind, n_nodes, n_edges, norm_blocks,
            slice_n, bps);

        int acc_blocks = NSLICE * ((slice_n + 3) / 4);
        accum_kernel<<<acc_blocks, threads, 0, stream>>>(
            (const float4*)state, nh, cursor, entries,
            (const float4*)w1, (const float4*)b1, (const float4*)w2, b2,
            (float4*)d_out, n_nodes, slice_n);
    } else {
        // fallback: edge-parallel with atomics into d_out
        float* nstate = (float*)d_ws;
        hipMemsetAsync(d_out, 0, (size_t)out_size * sizeof(float), stream);
        int norm_blocks = (n_nodes * 16 + threads - 1) / threads;
        norm_f32_kernel<<<norm_blocks, threads, 0, stream>>>(
            (const float4*)state, (float4*)nstate, n_nodes);
        long long total = (long long)n_edges * D;
        int edge_blocks = (int)((total + threads - 1) / threads);
        edge_kernel<<<edge_blocks, threads, 0, stream>>>(
            nstate, ind, w1, b1, w2, b2, (float*)d_out, n_edges);
        int node_blocks = (n_nodes * D + threads - 1) / threads;
        final_kernel<<<node_blocks, threads, 0, stream>>>(nstate, (float*)d_out, n_nodes);
    }
}

// Round 6
// 235.354 us; speedup vs baseline: 7.3783x; 1.0570x over previous
//
#include <hip/hip_runtime.h>

// Kuramoto graph kernel, MI355X (gfx950) — v6.
// state: [N,64] f32; ind: [E,2] int32; w1,b1,w2: [64] f32; b2: [1] f32.
// out: [N,64] f32.
//
// v6 = v5 structure with:
//   - build parallelism 4x (512 blocks/slice): 2.5M atomic->store latency
//     chains spread over ~1.15M threads (v5: 33% occupancy, VALUBusy 4.5%).
//   - dE lookup table: dE = f(s), s in [-1,1]; 2048-entry float2 lerp table
//     (16 KB, L1-resident) built by 8 fused blocks in prep. Accum inner loop
//     drops the 2nd 4-shfl reduce + 8 exp chains per edge.
//   - f16 normalized gather table, XCD-sliced CSR, fused projection (as v5).

#define D 64
#define CAP 128     // max degree; Poisson(50) tail at 128 ~ 5e-19
#define NSLICE 8
#define TAB 2048    // dE table entries

typedef _Float16 h4 __attribute__((ext_vector_type(4)));

// ---------- helpers ----------

__device__ __forceinline__ float grpReduce16(float v) {
    v += __shfl_xor(v, 1, 64);
    v += __shfl_xor(v, 2, 64);
    v += __shfl_xor(v, 4, 64);
    v += __shfl_xor(v, 8, 64);
    return v;
}

__device__ __forceinline__ float waveReduceSum64(float v) {
    v += __shfl_xor(v, 32, 64);
    v += __shfl_xor(v, 16, 64);
    v += __shfl_xor(v, 8, 64);
    v += __shfl_xor(v, 4, 64);
    v += __shfl_xor(v, 2, 64);
    v += __shfl_xor(v, 1, 64);
    return v;
}

__device__ __forceinline__ float dot4(float4 a, float4 b) {
    return fmaf(a.x, b.x, fmaf(a.y, b.y, fmaf(a.z, b.z, a.w * b.w)));
}

// gelu_tanh(x) = x * sigmoid(2t), t = sqrt(2/pi)*(x + 0.044715 x^3)
__device__ __forceinline__ float gelu_tanh(float x) {
    float u = -1.5957691216057308f * fmaf(0.044715f * x, x * x, x);  // -2t
    float e = __expf(u);
    return x * __builtin_amdgcn_rcpf(1.0f + e);
}

// ---------- fused prep: norm (f16 table) + dE table + sliced CSR build ----------

__global__ void __launch_bounds__(256) prep_kernel(
        const float4* __restrict__ state4,
        h4* __restrict__ nh,
        int* __restrict__ cursor,
        int* __restrict__ entries,
        const long long* __restrict__ ind_ll,
        const float* __restrict__ w1,
        const float* __restrict__ b1,
        const float* __restrict__ w2,
        const float* __restrict__ b2,
        float2* __restrict__ table2,
        int n_nodes, int n_edges, int norm_blocks,
        int slice_n, int blocks_per_slice) {
    int bid = blockIdx.x;
    int tid = threadIdx.x;

    if (bid < norm_blocks) {
        // --- norm: 16 rows per block, 16 lanes x float4 per row ---
        int row = bid * 16 + (tid >> 4);
        int gl  = tid & 15;
        if (row < n_nodes) {
            float4 v = state4[(size_t)row * 16 + gl];
            float ss = grpReduce16(dot4(v, v));
            float inv = 1.0f / sqrtf(ss);
            h4 hv;
            hv.x = (_Float16)(v.x * inv);
            hv.y = (_Float16)(v.y * inv);
            hv.z = (_Float16)(v.z * inv);
            hv.w = (_Float16)(v.w * inv);
            nh[(size_t)row * 16 + gl] = hv;
        }
        return;
    }

    if (bid < norm_blocks + 8) {
        // --- dE table: f(s) = sum_d gelu(s*w1+b1)*w2 + b2, s_i on [-1,1] ---
        int i = (bid - norm_blocks) * 256 + tid;   // 0..2047
        if (i < TAB) {
            const float step = 2.0f / (float)(TAB - 1);
            float s0 = fmaf((float)i, step, -1.0f);
            float s1 = s0 + step;
            float f0 = b2[0], f1 = f0;
            for (int d = 0; d < D; ++d) {
                float w1d = w1[d], b1d = b1[d], w2d = w2[d];
                f0 += gelu_tanh(fmaf(s0, w1d, b1d)) * w2d;
                f1 += gelu_tanh(fmaf(s1, w1d, b1d)) * w2d;
            }
            table2[i] = make_float2(f0, f1 - f0);   // (base, delta) for lerp
        }
        return;
    }

    // --- build: block (slice, j) scans edge chunk j, keeps slice's nodes ---
    int b = bid - norm_blocks - 8;
    int slice = b & (NSLICE - 1);
    int j = b >> 3;
    int lo = slice * slice_n;
    int hi = min(lo + slice_n, n_nodes);
    int e0 = (int)((long long)n_edges * j / blocks_per_slice);
    int e1 = (int)((long long)n_edges * (j + 1) / blocks_per_slice);

    for (int i = e0 + tid; i < e1; i += 256) {
        long long p = __builtin_nontemporal_load(ind_ll + i);
        int a = (int)p;
        int c = (int)(p >> 32);
        if (a >= lo && a < hi) {
            int s = atomicAdd(&cursor[a], 1);
            if (s < CAP) entries[(size_t)a * CAP + s] = c;
        }
        if (c >= lo && c < hi) {
            int s = atomicAdd(&cursor[c], 1);
            if (s < CAP) entries[(size_t)c * CAP + s] = a;
        }
    }
}

// ---------- accumulate + fused projection: one wave per node ----------

__global__ void __launch_bounds__(256) accum_kernel(
        const float4* __restrict__ state4,
        const h4* __restrict__ nh,
        const int* __restrict__ cursor,
        const int* __restrict__ entries,
        const float2* __restrict__ table2,
        float4* __restrict__ out4, int n_nodes, int slice_n) {
    int bid = blockIdx.x;
    int wid = threadIdx.x >> 6;
    int slice = bid & (NSLICE - 1);
    int local = (bid >> 3) * 4 + wid;
    if (local >= slice_n) return;
    int node = slice * slice_n + local;
    if (node >= n_nodes) return;

    int lane = threadIdx.x & 63;
    int grp  = lane >> 4;   // which of 4 neighbors per iteration
    int gl   = lane & 15;   // dims [4*gl .. 4*gl+3]

    // own row: read f32 state, normalize in-register
    float4 v = state4[(size_t)node * 16 + gl];
    float ss = grpReduce16(dot4(v, v));
    float inv = 1.0f / sqrtf(ss);
    float4 my = {v.x * inv, v.y * inv, v.z * inv, v.w * inv};

    int dg = min(cursor[node], CAP);
    const int* ebase = entries + (size_t)node * CAP;

    const float TS = 0.5f * (float)(TAB - 1);
    const float TMAX = (float)(TAB - 1) - 0.001f;

    float4 acc = {0.f, 0.f, 0.f, 0.f};
    #pragma unroll 2
    for (int k0 = 0; k0 < dg; k0 += 4) {
        int idx = k0 + grp;
        bool valid = idx < dg;
        int nbr = valid ? ebase[idx] : node;
        h4 xh = nh[(size_t)nbr * 16 + gl];
        float4 x = {(float)xh.x, (float)xh.y, (float)xh.z, (float)xh.w};

        float s = grpReduce16(dot4(my, x));

        // dE = lerp from table (all 16 lanes of a group hit the same entry)
        float u = fmaf(s, TS, TS);
        u = fminf(fmaxf(u, 0.0f), TMAX);
        int i0 = (int)u;
        float fr = u - (float)i0;
        float2 t = table2[i0];
        float dE = fmaf(fr, t.y, t.x);
        if (!valid) dE = 0.0f;

        acc.x = fmaf(dE, x.x, acc.x);
        acc.y = fmaf(dE, x.y, acc.y);
        acc.z = fmaf(dE, x.z, acc.z);
        acc.w = fmaf(dE, x.w, acc.w);
    }

    // sum the 4 groups' partials
    acc.x += __shfl_xor(acc.x, 16, 64); acc.x += __shfl_xor(acc.x, 32, 64);
    acc.y += __shfl_xor(acc.y, 16, 64); acc.y += __shfl_xor(acc.y, 32, 64);
    acc.z += __shfl_xor(acc.z, 16, 64); acc.z += __shfl_xor(acc.z, 32, 64);
    acc.w += __shfl_xor(acc.w, 16, 64); acc.w += __shfl_xor(acc.w, 32, 64);

    // out = n * <n, acc> - acc
    float d2 = grpReduce16(dot4(my, acc));
    float4 r;
    r.x = fmaf(my.x, d2, -acc.x);
    r.y = fmaf(my.y, d2, -acc.y);
    r.z = fmaf(my.z, d2, -acc.z);
    r.w = fmaf(my.w, d2, -acc.w);
    if (grp == 0) out4[(size_t)node * 16 + gl] = r;
}

// ---------- v1 fallback (edge-parallel, atomic output) ----------

__global__ void norm_f32_kernel(const float4* __restrict__ state4,
                                float4* __restrict__ nstate4, int n_nodes) {
    int gid = blockIdx.x * blockDim.x + threadIdx.x;
    int row = gid >> 4;
    int gl  = threadIdx.x & 15;
    if (row >= n_nodes) return;
    float4 v = state4[row * 16 + gl];
    float ss = grpReduce16(dot4(v, v));
    float inv = 1.0f / sqrtf(ss);
    float4 r = {v.x * inv, v.y * inv, v.z * inv, v.w * inv};
    nstate4[row * 16 + gl] = r;
}

__global__ void edge_kernel(const float* __restrict__ nstate,
                            const int* __restrict__ ind,
                            const float* __restrict__ w1,
                            const float* __restrict__ b1,
                            const float* __restrict__ w2,
                            const float* __restrict__ b2,
                            float* __restrict__ acc, int n_edges) {
    int gid = blockIdx.x * blockDim.x + threadIdx.x;
    int edge = gid >> 6;
    int lane = threadIdx.x & 63;
    if (edge >= n_edges) return;
    const int2 e = ((const int2*)ind)[edge];
    float sv = nstate[e.x * D + lane];
    float dv = nstate[e.y * D + lane];
    float s = waveReduceSum64(sv * dv);
    float x = fmaf(s, w1[lane], b1[lane]);
    float h = gelu_tanh(x) * w2[lane];
    float dE = waveReduceSum64(h) + b2[0];
    atomicAdd(&acc[e.x * D + lane], dE * dv);
    atomicAdd(&acc[e.y * D + lane], dE * sv);
}

__global__ void final_kernel(const float* __restrict__ nstate,
                             float* __restrict__ out, int n_nodes) {
    int gid = blockIdx.x * blockDim.x + threadIdx.x;
    int row = gid >> 6;
    int lane = threadIdx.x & 63;
    if (row >= n_nodes) return;
    float a = out[row * D + lane];
    float n = nstate[row * D + lane];
    float dot = waveReduceSum64(n * a);
    out[row * D + lane] = fmaf(n, dot, -a);
}

// ---------- launch ----------

extern "C" void kernel_launch(void* const* d_in, const int* in_sizes, int n_in,
                              void* d_out, int out_size, void* d_ws, size_t ws_size,
                              hipStream_t stream) {
    const float* state = (const float*)d_in[0];
    const int*   ind   = (const int*)d_in[1];
    const float* w1    = (const float*)d_in[2];
    const float* b1    = (const float*)d_in[3];
    const float* w2    = (const float*)d_in[4];
    const float* b2    = (const float*)d_in[5];

    int n_nodes = in_sizes[0] / D;
    int n_edges = in_sizes[1] / 2;
    int slice_n = (n_nodes + NSLICE - 1) / NSLICE;

    // workspace layout: f16 table + cursor + entries + dE table
    size_t nh_bytes      = (size_t)n_nodes * D * 2;            // 6.4 MB
    size_t cursor_off    = (nh_bytes + 255) & ~(size_t)255;
    size_t cursor_bytes  = (size_t)n_nodes * sizeof(int);
    size_t entries_off   = (cursor_off + cursor_bytes + 255) & ~(size_t)255;
    size_t entries_bytes = (size_t)n_nodes * CAP * sizeof(int);
    size_t table_off     = (entries_off + entries_bytes + 255) & ~(size_t)255;
    size_t table_bytes   = (size_t)TAB * sizeof(float2);
    size_t needed        = table_off + table_bytes;

    const int threads = 256;

    if (ws_size >= needed) {
        h4*     nh      = (h4*)d_ws;
        int*    cursor  = (int*)((char*)d_ws + cursor_off);
        int*    entries = (int*)((char*)d_ws + entries_off);
        float2* table2  = (float2*)((char*)d_ws + table_off);

        hipMemsetAsync(cursor, 0, cursor_bytes, stream);

        int norm_blocks = (((n_nodes + 15) / 16) + 7) & ~7;  // multiple of 8
        int bps = 512;                                       // build blocks per slice
        int grid = norm_blocks + 8 + bps * NSLICE;
        prep_kernel<<<grid, threads, 0, stream>>>(
            (const float4*)state, nh, cursor, entries,
            (const long long*)ind, w1, b1, w2, b2, table2,
            n_nodes, n_edges, norm_blocks, slice_n, bps);

        int acc_blocks = NSLICE * ((slice_n + 3) / 4);
        accum_kernel<<<acc_blocks, threads, 0, stream>>>(
            (const float4*)state, nh, cursor, entries, table2,
            (float4*)d_out, n_nodes, slice_n);
    } else {
        // fallback: edge-parallel with atomics into d_out
        float* nstate = (float*)d_ws;
        hipMemsetAsync(d_out, 0, (size_t)out_size * sizeof(float), stream);
        int norm_blocks = (n_nodes * 16 + threads - 1) / threads;
        norm_f32_kernel<<<norm_blocks, threads, 0, stream>>>(
            (const float4*)state, (float4*)nstate, n_nodes);
        long long total = (long long)n_edges * D;
        int edge_blocks = (int)((total + threads - 1) / threads);
        edge_kernel<<<edge_blocks, threads, 0, stream>>>(
            nstate, ind, w1, b1, w2, b2, (float*)d_out, n_edges);
        int node_blocks = (n_nodes * D + threads - 1) / threads;
        final_kernel<<<node_blocks, threads, 0, stream>>>(nstate, (float*)d_out, n_nodes);
    }
}

// Round 7
// 191.224 us; speedup vs baseline: 9.0810x; 1.2308x over previous
//
#include <hip/hip_runtime.h>

// Kuramoto graph kernel, MI355X (gfx950) — v7.
// state: [N,64] f32; ind: [E,2] int32; w1,b1,w2: [64] f32; b2: [1] f32.
// out: [N,64] f32.
//
// v7 = v6 with:
//   - uint16 entries (node ids fit 16 bits): slice entry region 3.2->1.6 MB
//     (fits XCD L2 alongside edge stream), halves scattered-store payload.
//   - unroll 4 in the build scan: 4 independent atomic->store chains/thread
//     (v6 prep was latency-bound: VALUBusy 6%, occ 77%, nothing saturated).
//   - accum in 8-lane groups: f16x8 16B row loads, 8 neighbors/iter,
//     3-step reduces, unroll 2 -> 2x memory-level parallelism.
//   - dE lerp table, XCD-sliced CSR, fused norm+table prep (as v6).

#define D 64
#define CAP 128     // max degree; Poisson(50) tail at 128 ~ 5e-19
#define NSLICE 8
#define TAB 2048    // dE table entries

typedef _Float16 h8 __attribute__((ext_vector_type(8)));
typedef float    f8 __attribute__((ext_vector_type(8)));

// ---------- helpers ----------

__device__ __forceinline__ float grpReduce8(float v) {
    v += __shfl_xor(v, 1, 64);
    v += __shfl_xor(v, 2, 64);
    v += __shfl_xor(v, 4, 64);
    return v;
}

__device__ __forceinline__ float grpReduce16(float v) {
    v += __shfl_xor(v, 1, 64);
    v += __shfl_xor(v, 2, 64);
    v += __shfl_xor(v, 4, 64);
    v += __shfl_xor(v, 8, 64);
    return v;
}

__device__ __forceinline__ float waveReduceSum64(float v) {
    v += __shfl_xor(v, 32, 64);
    v += __shfl_xor(v, 16, 64);
    v += __shfl_xor(v, 8, 64);
    v += __shfl_xor(v, 4, 64);
    v += __shfl_xor(v, 2, 64);
    v += __shfl_xor(v, 1, 64);
    return v;
}

__device__ __forceinline__ float dot4(float4 a, float4 b) {
    return fmaf(a.x, b.x, fmaf(a.y, b.y, fmaf(a.z, b.z, a.w * b.w)));
}

// gelu_tanh(x) = x * sigmoid(2t), t = sqrt(2/pi)*(x + 0.044715 x^3)
__device__ __forceinline__ float gelu_tanh(float x) {
    float u = -1.5957691216057308f * fmaf(0.044715f * x, x * x, x);  // -2t
    float e = __expf(u);
    return x * __builtin_amdgcn_rcpf(1.0f + e);
}

// ---------- fused prep: norm (f16x8 table) + dE table + sliced CSR build ----------

__global__ void __launch_bounds__(256) prep_kernel(
        const float4* __restrict__ state4,
        h8* __restrict__ nh,
        int* __restrict__ cursor,
        unsigned short* __restrict__ entries,
        const long long* __restrict__ ind_ll,
        const float* __restrict__ w1,
        const float* __restrict__ b1,
        const float* __restrict__ w2,
        const float* __restrict__ b2,
        float2* __restrict__ table2,
        int n_nodes, int n_edges, int norm_blocks,
        int slice_n, int blocks_per_slice) {
    int bid = blockIdx.x;
    int tid = threadIdx.x;

    if (bid < norm_blocks) {
        // --- norm: 32 rows per block, 8 lanes x (2 x float4) per row ---
        int row = bid * 32 + (tid >> 3);
        int gl  = tid & 7;
        if (row < n_nodes) {
            float4 va = state4[(size_t)row * 16 + 2 * gl];
            float4 vb = state4[(size_t)row * 16 + 2 * gl + 1];
            float ss = grpReduce8(dot4(va, va) + dot4(vb, vb));
            float inv = 1.0f / sqrtf(ss);
            h8 hv;
            hv[0] = (_Float16)(va.x * inv); hv[1] = (_Float16)(va.y * inv);
            hv[2] = (_Float16)(va.z * inv); hv[3] = (_Float16)(va.w * inv);
            hv[4] = (_Float16)(vb.x * inv); hv[5] = (_Float16)(vb.y * inv);
            hv[6] = (_Float16)(vb.z * inv); hv[7] = (_Float16)(vb.w * inv);
            nh[(size_t)row * 8 + gl] = hv;
        }
        return;
    }

    if (bid < norm_blocks + 8) {
        // --- dE table: f(s) = sum_d gelu(s*w1+b1)*w2 + b2, s on [-1,1] ---
        int i = (bid - norm_blocks) * 256 + tid;   // 0..2047
        if (i < TAB) {
            const float step = 2.0f / (float)(TAB - 1);
            float s0 = fmaf((float)i, step, -1.0f);
            float s1 = s0 + step;
            float f0 = b2[0], f1 = f0;
            for (int d = 0; d < D; ++d) {
                float w1d = w1[d], b1d = b1[d], w2d = w2[d];
                f0 += gelu_tanh(fmaf(s0, w1d, b1d)) * w2d;
                f1 += gelu_tanh(fmaf(s1, w1d, b1d)) * w2d;
            }
            table2[i] = make_float2(f0, f1 - f0);   // (base, delta) for lerp
        }
        return;
    }

    // --- build: block (slice, j) scans edge chunk j, keeps slice's nodes ---
    int b = bid - norm_blocks - 8;
    int slice = b & (NSLICE - 1);
    int j = b >> 3;
    int lo = slice * slice_n;
    int hi = min(lo + slice_n, n_nodes);
    int e0 = (int)((long long)n_edges * j / blocks_per_slice);
    int e1 = (int)((long long)n_edges * (j + 1) / blocks_per_slice);

    #pragma unroll 4
    for (int i = e0 + tid; i < e1; i += 256) {
        long long p = __builtin_nontemporal_load(ind_ll + i);
        int a = (int)p;
        int c = (int)(p >> 32);
        if (a >= lo && a < hi) {
            int s = atomicAdd(&cursor[a], 1);
            if (s < CAP) entries[(size_t)a * CAP + s] = (unsigned short)c;
        }
        if (c >= lo && c < hi) {
            int s = atomicAdd(&cursor[c], 1);
            if (s < CAP) entries[(size_t)c * CAP + s] = (unsigned short)a;
        }
    }
}

// ---------- accumulate + fused projection: one wave per node, 8-lane groups ----------

__global__ void __launch_bounds__(256) accum_kernel(
        const float4* __restrict__ state4,
        const h8* __restrict__ nh,
        const int* __restrict__ cursor,
        const unsigned short* __restrict__ entries,
        const float2* __restrict__ table2,
        float4* __restrict__ out4, int n_nodes, int slice_n) {
    int bid = blockIdx.x;
    int wid = threadIdx.x >> 6;
    int slice = bid & (NSLICE - 1);
    int local = (bid >> 3) * 4 + wid;
    if (local >= slice_n) return;
    int node = slice * slice_n + local;
    if (node >= n_nodes) return;

    int lane = threadIdx.x & 63;
    int grp  = lane >> 3;   // which of 8 neighbors per iteration
    int gl   = lane & 7;    // dims [8*gl .. 8*gl+7]

    // own row: read f32 state, normalize in-register
    float4 va = state4[(size_t)node * 16 + 2 * gl];
    float4 vb = state4[(size_t)node * 16 + 2 * gl + 1];
    float ss = grpReduce8(dot4(va, va) + dot4(vb, vb));
    float inv = 1.0f / sqrtf(ss);
    f8 my;
    my[0] = va.x * inv; my[1] = va.y * inv; my[2] = va.z * inv; my[3] = va.w * inv;
    my[4] = vb.x * inv; my[5] = vb.y * inv; my[6] = vb.z * inv; my[7] = vb.w * inv;

    int dg = min(cursor[node], CAP);
    const unsigned short* ebase = entries + (size_t)node * CAP;

    const float TS = 0.5f * (float)(TAB - 1);
    const float TMAX = (float)(TAB - 1) - 0.001f;

    f8 acc = {0.f, 0.f, 0.f, 0.f, 0.f, 0.f, 0.f, 0.f};
    #pragma unroll 2
    for (int k0 = 0; k0 < dg; k0 += 8) {
        int idx = k0 + grp;
        bool valid = idx < dg;
        int nbr = valid ? (int)ebase[idx] : node;
        h8 xh = nh[(size_t)nbr * 8 + gl];

        f8 x;
        float p = 0.f;
        #pragma unroll
        for (int q = 0; q < 8; ++q) {
            x[q] = (float)xh[q];
            p = fmaf(my[q], x[q], p);
        }
        float s = grpReduce8(p);

        // dE = lerp from table (8 lanes of a group hit the same entry)
        float u = fmaf(s, TS, TS);
        u = fminf(fmaxf(u, 0.0f), TMAX);
        int i0 = (int)u;
        float fr = u - (float)i0;
        float2 t = table2[i0];
        float dE = fmaf(fr, t.y, t.x);
        if (!valid) dE = 0.0f;

        #pragma unroll
        for (int q = 0; q < 8; ++q) acc[q] = fmaf(dE, x[q], acc[q]);
    }

    // sum the 8 groups' partials (xor 8,16,32)
    #pragma unroll
    for (int q = 0; q < 8; ++q) {
        float t = acc[q];
        t += __shfl_xor(t, 8, 64);
        t += __shfl_xor(t, 16, 64);
        t += __shfl_xor(t, 32, 64);
        acc[q] = t;
    }

    // out = n * <n, acc> - acc
    float p2 = 0.f;
    #pragma unroll
    for (int q = 0; q < 8; ++q) p2 = fmaf(my[q], acc[q], p2);
    float d2 = grpReduce8(p2);

    if (grp == 0) {
        float4 ra, rb;
        ra.x = fmaf(my[0], d2, -acc[0]); ra.y = fmaf(my[1], d2, -acc[1]);
        ra.z = fmaf(my[2], d2, -acc[2]); ra.w = fmaf(my[3], d2, -acc[3]);
        rb.x = fmaf(my[4], d2, -acc[4]); rb.y = fmaf(my[5], d2, -acc[5]);
        rb.z = fmaf(my[6], d2, -acc[6]); rb.w = fmaf(my[7], d2, -acc[7]);
        out4[(size_t)node * 16 + 2 * gl]     = ra;
        out4[(size_t)node * 16 + 2 * gl + 1] = rb;
    }
}

// ---------- v1 fallback (edge-parallel, atomic output) ----------

__global__ void norm_f32_kernel(const float4* __restrict__ state4,
                                float4* __restrict__ nstate4, int n_nodes) {
    int gid = blockIdx.x * blockDim.x + threadIdx.x;
    int row = gid >> 4;
    int gl  = threadIdx.x & 15;
    if (row >= n_nodes) return;
    float4 v = state4[row * 16 + gl];
    float ss = grpReduce16(dot4(v, v));
    float inv = 1.0f / sqrtf(ss);
    float4 r = {v.x * inv, v.y * inv, v.z * inv, v.w * inv};
    nstate4[row * 16 + gl] = r;
}

__global__ void edge_kernel(const float* __restrict__ nstate,
                            const int* __restrict__ ind,
                            const float* __restrict__ w1,
                            const float* __restrict__ b1,
                            const float* __restrict__ w2,
                            const float* __restrict__ b2,
                            float* __restrict__ acc, int n_edges) {
    int gid = blockIdx.x * blockDim.x + threadIdx.x;
    int edge = gid >> 6;
    int lane = threadIdx.x & 63;
    if (edge >= n_edges) return;
    const int2 e = ((const int2*)ind)[edge];
    float sv = nstate[e.x * D + lane];
    float dv = nstate[e.y * D + lane];
    float s = waveReduceSum64(sv * dv);
    float x = fmaf(s, w1[lane], b1[lane]);
    float h = gelu_tanh(x) * w2[lane];
    float dE = waveReduceSum64(h) + b2[0];
    atomicAdd(&acc[e.x * D + lane], dE * dv);
    atomicAdd(&acc[e.y * D + lane], dE * sv);
}

__global__ void final_kernel(const float* __restrict__ nstate,
                             float* __restrict__ out, int n_nodes) {
    int gid = blockIdx.x * blockDim.x + threadIdx.x;
    int row = gid >> 6;
    int lane = threadIdx.x & 63;
    if (row >= n_nodes) return;
    float a = out[row * D + lane];
    float n = nstate[row * D + lane];
    float dot = waveReduceSum64(n * a);
    out[row * D + lane] = fmaf(n, dot, -a);
}

// ---------- launch ----------

extern "C" void kernel_launch(void* const* d_in, const int* in_sizes, int n_in,
                              void* d_out, int out_size, void* d_ws, size_t ws_size,
                              hipStream_t stream) {
    const float* state = (const float*)d_in[0];
    const int*   ind   = (const int*)d_in[1];
    const float* w1    = (const float*)d_in[2];
    const float* b1    = (const float*)d_in[3];
    const float* w2    = (const float*)d_in[4];
    const float* b2    = (const float*)d_in[5];

    int n_nodes = in_sizes[0] / D;
    int n_edges = in_sizes[1] / 2;
    int slice_n = (n_nodes + NSLICE - 1) / NSLICE;

    // workspace layout: f16 row table + cursor + u16 entries + dE table
    size_t nh_bytes      = (size_t)n_nodes * D * 2;            // 6.4 MB
    size_t cursor_off    = (nh_bytes + 255) & ~(size_t)255;
    size_t cursor_bytes  = (size_t)n_nodes * sizeof(int);
    size_t entries_off   = (cursor_off + cursor_bytes + 255) & ~(size_t)255;
    size_t entries_bytes = (size_t)n_nodes * CAP * 2;          // 12.8 MB
    size_t table_off     = (entries_off + entries_bytes + 255) & ~(size_t)255;
    size_t table_bytes   = (size_t)TAB * sizeof(float2);
    size_t needed        = table_off + table_bytes;

    const int threads = 256;

    if (ws_size >= needed && n_nodes <= 65535) {
        h8*             nh      = (h8*)d_ws;
        int*            cursor  = (int*)((char*)d_ws + cursor_off);
        unsigned short* entries = (unsigned short*)((char*)d_ws + entries_off);
        float2*         table2  = (float2*)((char*)d_ws + table_off);

        hipMemsetAsync(cursor, 0, cursor_bytes, stream);

        int norm_blocks = (((n_nodes + 31) / 32) + 7) & ~7;  // multiple of 8
        int bps = 512;                                       // build blocks per slice
        int grid = norm_blocks + 8 + bps * NSLICE;
        prep_kernel<<<grid, threads, 0, stream>>>(
            (const float4*)state, nh, cursor, entries,
            (const long long*)ind, w1, b1, w2, b2, table2,
            n_nodes, n_edges, norm_blocks, slice_n, bps);

        int acc_blocks = NSLICE * ((slice_n + 3) / 4);
        accum_kernel<<<acc_blocks, threads, 0, stream>>>(
            (const float4*)state, nh, cursor, entries, table2,
            (float4*)d_out, n_nodes, slice_n);
    } else {
        // fallback: edge-parallel with atomics into d_out
        float* nstate = (float*)d_ws;
        hipMemsetAsync(d_out, 0, (size_t)out_size * sizeof(float), stream);
        int norm_blocks = (n_nodes * 16 + threads - 1) / threads;
        norm_f32_kernel<<<norm_blocks, threads, 0, stream>>>(
            (const float4*)state, (float4*)nstate, n_nodes);
        long long total = (long long)n_edges * D;
        int edge_blocks = (int)((total + threads - 1) / threads);
        edge_kernel<<<edge_blocks, threads, 0, stream>>>(
            nstate, ind, w1, b1, w2, b2, (float*)d_out, n_edges);
        int node_blocks = (n_nodes * D + threads - 1) / threads;
        final_kernel<<<node_blocks, threads, 0, stream>>>(nstate, (float*)d_out, n_nodes);
    }
}